// Round 1
// baseline (2277.311 us; speedup 1.0000x reference)
//
#include <hip/hip_runtime.h>
#include <hip/hip_bf16.h>

#define BB 16
#define SS 4096
#define EE 128
#define DMM 64
#define HH_ 8
#define DHH 8
#define FFF 256
#define LLAY 8
#define CC 1623
#define NTOK (BB*SS)
#define NSPLIT 4

__device__ __forceinline__ void wave_stats(float v, float& mean, float& var) {
  float s = v, s2 = v * v;
  #pragma unroll
  for (int m = 32; m; m >>= 1) {
    s  += __shfl_xor(s,  m, 64);
    s2 += __shfl_xor(s2, m, 64);
  }
  mean = s * (1.0f / 64.0f);
  var  = s2 * (1.0f / 64.0f) - mean * mean;
}

__device__ __forceinline__ float gelu_tanh(float x) {
  float u = 0.7978845608028654f * (x + 0.044715f * x * x * x);
  float t = 1.0f - 2.0f / (__expf(2.0f * u) + 1.0f);   // tanh(u)
  return 0.5f * x * (1.0f + t);
}

__device__ __forceinline__ float phi_elu(float x) {   // elu(x)+1
  return x > 0.0f ? x + 1.0f : __expf(x);
}

// ---------------------------------------------------------------------------
// hh = examples @ we + be + label_emb[labels]; hh = hh @ w_in + b_in
// 16 tokens / 256-thread block.
// ---------------------------------------------------------------------------
__global__ __launch_bounds__(256) void k_embed(
    const float* __restrict__ ex, const int* __restrict__ labels,
    const float* __restrict__ we, const float* __restrict__ be,
    const float* __restrict__ lemb, const float* __restrict__ w_in,
    const float* __restrict__ b_in, float* __restrict__ hh)
{
  __shared__ float exL[16][128];
  __shared__ float embL[16][128];
  const int tid = threadIdx.x;
  const int t0 = blockIdx.x * 16;

  #pragma unroll
  for (int i = 0; i < 8; ++i) {
    int idx = tid + 256 * i;
    int t = idx >> 7, k = idx & 127;
    exL[t][k] = ex[(size_t)(t0 + t) * EE + k];
  }
  __syncthreads();

  {
    const int j = tid & 127, h2 = tid >> 7;
    float acc[8];
    #pragma unroll
    for (int m = 0; m < 8; ++m) acc[m] = 0.0f;
    for (int k = 0; k < 128; k += 4) {
      float w0 = we[(k + 0) * 128 + j];
      float w1 = we[(k + 1) * 128 + j];
      float w2 = we[(k + 2) * 128 + j];
      float w3 = we[(k + 3) * 128 + j];
      #pragma unroll
      for (int m = 0; m < 8; ++m) {
        int t = h2 * 8 + m;
        float4 x = *(const float4*)&exL[t][k];
        acc[m] += x.x * w0 + x.y * w1 + x.z * w2 + x.w * w3;
      }
    }
    #pragma unroll
    for (int m = 0; m < 8; ++m) {
      int t = h2 * 8 + m;
      int lbl = labels[t0 + t];
      embL[t][j] = acc[m] + be[j] + lemb[(size_t)lbl * EE + j];
    }
  }
  __syncthreads();

  {
    const int j = tid & 63, g = tid >> 6;
    float acc[4];
    #pragma unroll
    for (int m = 0; m < 4; ++m) acc[m] = 0.0f;
    for (int k = 0; k < 128; k += 4) {
      float w0 = w_in[(k + 0) * 64 + j];
      float w1 = w_in[(k + 1) * 64 + j];
      float w2 = w_in[(k + 2) * 64 + j];
      float w3 = w_in[(k + 3) * 64 + j];
      #pragma unroll
      for (int m = 0; m < 4; ++m) {
        int t = g + 4 * m;
        float4 x = *(const float4*)&embL[t][k];
        acc[m] += x.x * w0 + x.y * w1 + x.z * w2 + x.w * w3;
      }
    }
    #pragma unroll
    for (int m = 0; m < 4; ++m) {
      int t = g + 4 * m;
      hh[(size_t)(t0 + t) * DMM + j] = acc[m] + b_in[j];
    }
  }
}

// ---------------------------------------------------------------------------
// x = LN1(mask*hh); q,k,v = x@W + b; pq=phi(q), pk=phi(k)*mask, v
// ---------------------------------------------------------------------------
__global__ __launch_bounds__(256) void k_pre(
    const float* __restrict__ hh, const float* __restrict__ mask,
    const float* __restrict__ g1, const float* __restrict__ b1,
    const float* __restrict__ wq, const float* __restrict__ bq,
    const float* __restrict__ wk, const float* __restrict__ bk,
    const float* __restrict__ wv, const float* __restrict__ bv,
    float* __restrict__ pq, float* __restrict__ pk, float* __restrict__ vv)
{
  __shared__ float xL[16][64];
  const int tid = threadIdx.x;
  const int t0 = blockIdx.x * 16;

  #pragma unroll
  for (int i = 0; i < 4; ++i) {
    int idx = tid + 256 * i;
    int t = idx >> 6, k = idx & 63;
    xL[t][k] = hh[(size_t)(t0 + t) * DMM + k] * mask[t0 + t];
  }
  __syncthreads();

  const int lane = tid & 63, w = tid >> 6;
  #pragma unroll
  for (int m = 0; m < 4; ++m) {
    int t = w + 4 * m;
    float v = xL[t][lane];
    float mean, var; wave_stats(v, mean, var);
    xL[t][lane] = (v - mean) * rsqrtf(var + 1e-5f) * g1[lane] + b1[lane];
  }
  __syncthreads();

  const int j = lane, g = w;
  float aq[4], ak[4], av[4];
  #pragma unroll
  for (int m = 0; m < 4; ++m) { aq[m] = 0.0f; ak[m] = 0.0f; av[m] = 0.0f; }
  for (int k = 0; k < 64; k += 4) {
    float q0 = wq[(k + 0) * 64 + j], q1 = wq[(k + 1) * 64 + j];
    float q2 = wq[(k + 2) * 64 + j], q3 = wq[(k + 3) * 64 + j];
    float k0 = wk[(k + 0) * 64 + j], k1 = wk[(k + 1) * 64 + j];
    float k2 = wk[(k + 2) * 64 + j], k3 = wk[(k + 3) * 64 + j];
    float v0 = wv[(k + 0) * 64 + j], v1 = wv[(k + 1) * 64 + j];
    float v2 = wv[(k + 2) * 64 + j], v3 = wv[(k + 3) * 64 + j];
    #pragma unroll
    for (int m = 0; m < 4; ++m) {
      int t = g + 4 * m;
      float4 x = *(const float4*)&xL[t][k];
      aq[m] += x.x * q0 + x.y * q1 + x.z * q2 + x.w * q3;
      ak[m] += x.x * k0 + x.y * k1 + x.z * k2 + x.w * k3;
      av[m] += x.x * v0 + x.y * v1 + x.z * v2 + x.w * v3;
    }
  }
  #pragma unroll
  for (int m = 0; m < 4; ++m) {
    int t = g + 4 * m;
    size_t o = (size_t)(t0 + t) * DMM + j;
    float mv = mask[t0 + t];
    pq[o] = phi_elu(aq[m] + bq[j]);
    pk[o] = phi_elu(ak[m] + bk[j]) * mv;
    vv[o] = av[m] + bv[j];
  }
}

// ---------------------------------------------------------------------------
// kv[b,h,d,e] = sum_s pk[b,s,h,d]*v[b,s,h,e]; ksum[b,h,d] = sum_s pk[b,s,h,d]
// grid = (B*H*NSPLIT); register 8x8 outer product per lane, wave butterfly.
// partial[bh*NSPLIT+sp][72]  (0..63 = kv, 64..71 = ksum)
// ---------------------------------------------------------------------------
__global__ __launch_bounds__(256) void k_kv(
    const float* __restrict__ pk, const float* __restrict__ vv,
    float* __restrict__ part)
{
  const int bh = blockIdx.x / NSPLIT, sp = blockIdx.x % NSPLIT;
  const int b = bh >> 3, h = bh & 7;
  const int tid = threadIdx.x;
  const int lane = tid & 63, w = tid >> 6;

  float kv[8][8];
  float ks[8];
  #pragma unroll
  for (int d = 0; d < 8; ++d) {
    ks[d] = 0.0f;
    #pragma unroll
    for (int e = 0; e < 8; ++e) kv[d][e] = 0.0f;
  }

  const int sbase = sp * (SS / NSPLIT) + w * (SS / NSPLIT / 4);
  for (int it = 0; it < SS / NSPLIT / 4 / 64; ++it) {
    int s = sbase + it * 64 + lane;
    size_t o = ((size_t)b * SS + s) * DMM + h * 8;
    float4 p0 = *(const float4*)&pk[o];
    float4 p1 = *(const float4*)&pk[o + 4];
    float4 u0 = *(const float4*)&vv[o];
    float4 u1 = *(const float4*)&vv[o + 4];
    float p[8] = {p0.x, p0.y, p0.z, p0.w, p1.x, p1.y, p1.z, p1.w};
    float u[8] = {u0.x, u0.y, u0.z, u0.w, u1.x, u1.y, u1.z, u1.w};
    #pragma unroll
    for (int d = 0; d < 8; ++d) {
      ks[d] += p[d];
      #pragma unroll
      for (int e = 0; e < 8; ++e) kv[d][e] += p[d] * u[e];
    }
  }

  #pragma unroll
  for (int mk = 32; mk; mk >>= 1) {
    #pragma unroll
    for (int d = 0; d < 8; ++d) {
      ks[d] += __shfl_xor(ks[d], mk, 64);
      #pragma unroll
      for (int e = 0; e < 8; ++e) kv[d][e] += __shfl_xor(kv[d][e], mk, 64);
    }
  }

  __shared__ float red[4][72];
  if (lane == 0) {
    #pragma unroll
    for (int d = 0; d < 8; ++d) {
      red[w][64 + d] = ks[d];
      #pragma unroll
      for (int e = 0; e < 8; ++e) red[w][d * 8 + e] = kv[d][e];
    }
  }
  __syncthreads();
  if (tid < 72) {
    float s = red[0][tid] + red[1][tid] + red[2][tid] + red[3][tid];
    part[(size_t)blockIdx.x * 72 + tid] = s;
  }
}

// ---------------------------------------------------------------------------
// att = (pq@kv)/(pq.ksum+eps); hh = mask*hh + att@wo + bo;
// y = LN2(hh); hh += gelu(y@w1+b1)@w2 + b2
// ---------------------------------------------------------------------------
__global__ __launch_bounds__(256) void k_post(
    float* __restrict__ hh, const float* __restrict__ mask,
    const float* __restrict__ part, const float* __restrict__ pq,
    const float* __restrict__ wo, const float* __restrict__ bo,
    const float* __restrict__ g2, const float* __restrict__ b2ln,
    const float* __restrict__ w1, const float* __restrict__ b1f,
    const float* __restrict__ w2, const float* __restrict__ b2f)
{
  __shared__ float kvL[576];        // [h][72]
  __shared__ float pqL[16][64];
  __shared__ float hhL[16][64];
  __shared__ float yT[64][20];      // transposed LN2 out, padded stride
  __shared__ float tfL[16][256];    // gelu intermediates; first 16x64 doubles as attL
  float* attL = (float*)tfL;

  const int tid = threadIdx.x;
  const int t0 = blockIdx.x * 16;
  const int b = t0 >> 12;

  for (int r = tid; r < 576; r += 256) {
    int h = r / 72, rr = r - h * 72;
    const float* p = part + ((size_t)(b * HH_ + h) * NSPLIT) * 72 + rr;
    kvL[r] = p[0] + p[72] + p[144] + p[216];
  }
  #pragma unroll
  for (int i = 0; i < 4; ++i) {
    int idx = tid + 256 * i;
    int t = idx >> 6, k = idx & 63;
    pqL[t][k] = pq[(size_t)(t0 + t) * DMM + k];
    hhL[t][k] = hh[(size_t)(t0 + t) * DMM + k] * mask[t0 + t];
  }
  __syncthreads();

  const int j = tid & 63, g = tid >> 6;
  {
    const int h = j >> 3, e = j & 7;
    #pragma unroll
    for (int m = 0; m < 4; ++m) {
      int t = g + 4 * m;
      float num = 0.0f, den = 1e-6f;
      #pragma unroll
      for (int d = 0; d < 8; ++d) {
        float p = pqL[t][h * 8 + d];
        num += p * kvL[h * 72 + d * 8 + e];
        den += p * kvL[h * 72 + 64 + d];
      }
      attL[t * 64 + j] = num / den;
    }
  }
  __syncthreads();

  {
    float acc[4];
    #pragma unroll
    for (int m = 0; m < 4; ++m) acc[m] = hhL[g + 4 * m][j];
    for (int k = 0; k < 64; k += 4) {
      float w0 = wo[(k + 0) * 64 + j], w1v = wo[(k + 1) * 64 + j];
      float w2v = wo[(k + 2) * 64 + j], w3 = wo[(k + 3) * 64 + j];
      #pragma unroll
      for (int m = 0; m < 4; ++m) {
        int t = g + 4 * m;
        float4 a = *(const float4*)&attL[t * 64 + k];
        acc[m] += a.x * w0 + a.y * w1v + a.z * w2v + a.w * w3;
      }
    }
    #pragma unroll
    for (int m = 0; m < 4; ++m) hhL[g + 4 * m][j] = acc[m] + bo[j];
  }
  __syncthreads();

  // LN2 -> yT (wave g owns tokens g, g+4, g+8, g+12)
  #pragma unroll
  for (int m = 0; m < 4; ++m) {
    int t = g + 4 * m;
    float v = hhL[t][j];
    float mean, var; wave_stats(v, mean, var);
    yT[j][t] = (v - mean) * rsqrtf(var + 1e-5f) * g2[j] + b2ln[j];
  }
  __syncthreads();

  // FFN1: thread owns ff column tid for all 16 tokens
  {
    float af[16];
    #pragma unroll
    for (int t = 0; t < 16; ++t) af[t] = 0.0f;
    for (int k = 0; k < 64; ++k) {
      float wv = w1[k * 256 + tid];
      #pragma unroll
      for (int tq = 0; tq < 4; ++tq) {
        float4 y = *(const float4*)&yT[k][tq * 4];
        af[tq * 4 + 0] += y.x * wv;
        af[tq * 4 + 1] += y.y * wv;
        af[tq * 4 + 2] += y.z * wv;
        af[tq * 4 + 3] += y.w * wv;
      }
    }
    float bb1 = b1f[tid];
    #pragma unroll
    for (int t = 0; t < 16; ++t) tfL[t][tid] = gelu_tanh(af[t] + bb1);
  }
  __syncthreads();

  // FFN2 + residual + store
  {
    float acc[4];
    #pragma unroll
    for (int m = 0; m < 4; ++m) acc[m] = hhL[g + 4 * m][j];
    for (int k = 0; k < 256; k += 4) {
      float w0 = w2[(k + 0) * 64 + j], w1v = w2[(k + 1) * 64 + j];
      float w2v = w2[(k + 2) * 64 + j], w3 = w2[(k + 3) * 64 + j];
      #pragma unroll
      for (int m = 0; m < 4; ++m) {
        int t = g + 4 * m;
        float4 a = *(const float4*)&tfL[t][k];
        acc[m] += a.x * w0 + a.y * w1v + a.z * w2v + a.w * w3;
      }
    }
    #pragma unroll
    for (int m = 0; m < 4; ++m) {
      int t = g + 4 * m;
      hh[(size_t)(t0 + t) * DMM + j] = acc[m] + b2f[j];
    }
  }
}

// ---------------------------------------------------------------------------
// x = LNf(hh)*mask; out = x@w_out + b_out
// grid (4 col-tiles of 512, NTOK/16); thread owns cols cA=cbase+tid, cB=cA+256
// ---------------------------------------------------------------------------
__global__ __launch_bounds__(256) void k_final(
    const float* __restrict__ hh, const float* __restrict__ mask,
    const float* __restrict__ gf, const float* __restrict__ bf,
    const float* __restrict__ wout, const float* __restrict__ bout,
    float* __restrict__ out)
{
  __shared__ float xL[16][64];
  const int tid = threadIdx.x;
  const int t0 = blockIdx.y * 16;

  #pragma unroll
  for (int i = 0; i < 4; ++i) {
    int idx = tid + 256 * i;
    int t = idx >> 6, k = idx & 63;
    xL[t][k] = hh[(size_t)(t0 + t) * DMM + k];
  }
  __syncthreads();

  const int lane = tid & 63, w = tid >> 6;
  #pragma unroll
  for (int m = 0; m < 4; ++m) {
    int t = w + 4 * m;
    float v = xL[t][lane];
    float mean, var; wave_stats(v, mean, var);
    xL[t][lane] = ((v - mean) * rsqrtf(var + 1e-5f) * gf[lane] + bf[lane]) * mask[t0 + t];
  }
  __syncthreads();

  const int cA = blockIdx.x * 512 + tid;
  const int cB = cA + 256;
  const int cAc = cA < CC ? cA : CC - 1;
  const int cBc = cB < CC ? cB : CC - 1;

  float acc0[16], acc1[16];
  #pragma unroll
  for (int t = 0; t < 16; ++t) { acc0[t] = 0.0f; acc1[t] = 0.0f; }

  for (int k = 0; k < 64; k += 4) {
    float wa0 = wout[(size_t)(k + 0) * CC + cAc];
    float wa1 = wout[(size_t)(k + 1) * CC + cAc];
    float wa2 = wout[(size_t)(k + 2) * CC + cAc];
    float wa3 = wout[(size_t)(k + 3) * CC + cAc];
    float wb0 = wout[(size_t)(k + 0) * CC + cBc];
    float wb1 = wout[(size_t)(k + 1) * CC + cBc];
    float wb2 = wout[(size_t)(k + 2) * CC + cBc];
    float wb3 = wout[(size_t)(k + 3) * CC + cBc];
    #pragma unroll
    for (int t = 0; t < 16; ++t) {
      float4 x = *(const float4*)&xL[t][k];
      acc0[t] += x.x * wa0 + x.y * wa1 + x.z * wa2 + x.w * wa3;
      acc1[t] += x.x * wb0 + x.y * wb1 + x.z * wb2 + x.w * wb3;
    }
  }

  float ba = bout[cAc], bb = bout[cBc];
  #pragma unroll
  for (int t = 0; t < 16; ++t) {
    size_t o = (size_t)(t0 + t) * CC;
    if (cA < CC) out[o + cA] = acc0[t] + ba;
    if (cB < CC) out[o + cB] = acc1[t] + bb;
  }
}

// ---------------------------------------------------------------------------

extern "C" void kernel_launch(void* const* d_in, const int* in_sizes, int n_in,
                              void* d_out, int out_size, void* d_ws, size_t ws_size,
                              hipStream_t stream) {
  (void)in_sizes; (void)n_in; (void)out_size; (void)ws_size;
  const float* ex    = (const float*)d_in[0];
  const int*   labels= (const int*)  d_in[1];
  const float* mask  = (const float*)d_in[2];
  const float* we    = (const float*)d_in[3];
  const float* be    = (const float*)d_in[4];
  const float* lemb  = (const float*)d_in[5];
  const float* w_in  = (const float*)d_in[6];
  const float* b_in  = (const float*)d_in[7];
  const float* ln1s  = (const float*)d_in[8];
  const float* ln1b  = (const float*)d_in[9];
  const float* wq    = (const float*)d_in[10];
  const float* bq    = (const float*)d_in[11];
  const float* wk    = (const float*)d_in[12];
  const float* bk    = (const float*)d_in[13];
  const float* wv    = (const float*)d_in[14];
  const float* bv    = (const float*)d_in[15];
  const float* wo    = (const float*)d_in[16];
  const float* bo    = (const float*)d_in[17];
  const float* ln2s  = (const float*)d_in[18];
  const float* ln2b  = (const float*)d_in[19];
  const float* w1    = (const float*)d_in[20];
  const float* b1    = (const float*)d_in[21];
  const float* w2    = (const float*)d_in[22];
  const float* b2    = (const float*)d_in[23];
  const float* lnfs  = (const float*)d_in[24];
  const float* lnfb  = (const float*)d_in[25];
  const float* wout  = (const float*)d_in[26];
  const float* bout  = (const float*)d_in[27];

  float* ws = (float*)d_ws;
  const size_t NC = (size_t)NTOK * DMM;
  float* hh   = ws;
  float* pqb  = ws + NC;
  float* pkb  = ws + 2 * NC;
  float* vvb  = ws + 3 * NC;
  float* part = ws + 4 * NC;   // B*H*NSPLIT*72 floats

  k_embed<<<NTOK / 16, 256, 0, stream>>>(ex, labels, we, be, lemb, w_in, b_in, hh);

  for (int i = 0; i < LLAY; ++i) {
    k_pre<<<NTOK / 16, 256, 0, stream>>>(
        hh, mask, ln1s + i * DMM, ln1b + i * DMM,
        wq + (size_t)i * DMM * DMM, bq + i * DMM,
        wk + (size_t)i * DMM * DMM, bk + i * DMM,
        wv + (size_t)i * DMM * DMM, bv + i * DMM,
        pqb, pkb, vvb);
    k_kv<<<BB * HH_ * NSPLIT, 256, 0, stream>>>(pkb, vvb, part);
    k_post<<<NTOK / 16, 256, 0, stream>>>(
        hh, mask, part, pqb,
        wo + (size_t)i * DMM * DMM, bo + i * DMM,
        ln2s + i * DMM, ln2b + i * DMM,
        w1 + (size_t)i * DMM * FFF, b1 + i * FFF,
        w2 + (size_t)i * FFF * DMM, b2 + i * DMM);
  }

  k_final<<<dim3(4, NTOK / 16), 256, 0, stream>>>(
      hh, mask, lnfs, lnfb, wout, bout, (float*)d_out);
}

// Round 2
// 1499.345 us; speedup vs baseline: 1.5189x; 1.5189x over previous
//
#include <hip/hip_runtime.h>
#include <hip/hip_bf16.h>

#define BB 16
#define SS 4096
#define EE 128
#define DMM 64
#define HH_ 8
#define FFF 256
#define LLAY 8
#define CC 1623
#define NTOK (BB*SS)
#define NSPLIT 4

typedef __attribute__((ext_vector_type(8))) short bf8v;   // 8 bf16
typedef __attribute__((ext_vector_type(4))) float f4;

__device__ __forceinline__ f4 MFMA(bf8v a, bf8v b, f4 c) {
  return __builtin_amdgcn_mfma_f32_16x16x32_bf16(a, b, c, 0, 0, 0);
}

__device__ __forceinline__ float bf2f(ushort u) {
  union { uint i; float f; } x; x.i = (uint)u << 16; return x.f;
}
__device__ __forceinline__ ushort f2bf(float f) {
  union { float f; uint i; } x; x.f = f;
  return (ushort)((x.i + 0x7fffu + ((x.i >> 16) & 1u)) >> 16);   // RNE
}

__device__ __forceinline__ void wave_stats(float v, float& mean, float& var) {
  float s = v, s2 = v * v;
  #pragma unroll
  for (int m = 32; m; m >>= 1) {
    s  += __shfl_xor(s,  m, 64);
    s2 += __shfl_xor(s2, m, 64);
  }
  mean = s * (1.0f / 64.0f);
  var  = s2 * (1.0f / 64.0f) - mean * mean;
}

__device__ __forceinline__ float gelu_tanh(float x) {
  float u = 0.7978845608028654f * (x + 0.044715f * x * x * x);
  float t = 1.0f - 2.0f / (__expf(2.0f * u) + 1.0f);
  return 0.5f * x * (1.0f + t);
}
__device__ __forceinline__ float phi_elu(float x) { return x > 0.0f ? x + 1.0f : __expf(x); }

// ---------------------------------------------------------------------------
// W[K][N] fp32 -> Wt[N][K] bf16 (batched over gridDim.y layers)
// ---------------------------------------------------------------------------
__global__ __launch_bounds__(256) void k_convT(
    const float* __restrict__ W, ushort* __restrict__ Wt, int K, int N)
{
  const size_t base = (size_t)blockIdx.y * K * N;
  int idx = blockIdx.x * 256 + threadIdx.x;
  if (idx >= K * N) return;
  int k = idx / N, n = idx - k * N;
  Wt[base + (size_t)n * K + k] = f2bf(W[base + idx]);
}

// ---------------------------------------------------------------------------
// hh = (ex@we + be + lemb[labels]) @ w_in + b_in   (64 tokens / block)
// ---------------------------------------------------------------------------
__global__ __launch_bounds__(512) void k_embed(
    const float* __restrict__ ex, const int* __restrict__ labels,
    const ushort* __restrict__ wet, const float* __restrict__ be,
    const float* __restrict__ lemb, const ushort* __restrict__ wint,
    const float* __restrict__ b_in, float* __restrict__ hh)
{
  __shared__ ushort exL[64][136];
  __shared__ ushort embL[64][136];
  __shared__ int labL[64];
  const int tid = threadIdx.x, lane = tid & 63, w = tid >> 6;
  const int t0 = blockIdx.x * 64;

  if (tid < 64) labL[tid] = labels[t0 + tid];
  #pragma unroll
  for (int i = 0; i < 16; ++i) {
    int idx = tid + 512 * i;
    int t = idx >> 7, k = idx & 127;
    exL[t][k] = f2bf(ex[(size_t)(t0 + t) * EE + k]);
  }
  __syncthreads();

  const int col = lane & 15, quad = lane >> 4;
  const int m0 = (w >> 1) * 16, nh = w & 1;

  {
    bf8v a[4];
    #pragma unroll
    for (int kf = 0; kf < 4; ++kf)
      a[kf] = *(const bf8v*)&exL[m0 + col][kf * 32 + quad * 8];
    #pragma unroll
    for (int nt = 0; nt < 4; ++nt) {
      int n0 = nh * 64 + nt * 16;
      const ushort* bp = wet + (size_t)(n0 + col) * 128 + quad * 8;
      f4 acc = {0.f, 0.f, 0.f, 0.f};
      #pragma unroll
      for (int kf = 0; kf < 4; ++kf)
        acc = MFMA(a[kf], *(const bf8v*)(bp + kf * 32), acc);
      int c = n0 + col;
      float bev = be[c];
      #pragma unroll
      for (int r = 0; r < 4; ++r) {
        int tl = m0 + quad * 4 + r;
        embL[tl][c] = f2bf(acc[r] + bev + lemb[(size_t)labL[tl] * EE + c]);
      }
    }
  }
  __syncthreads();

  {
    bf8v a[4];
    #pragma unroll
    for (int kf = 0; kf < 4; ++kf)
      a[kf] = *(const bf8v*)&embL[m0 + col][kf * 32 + quad * 8];
    #pragma unroll
    for (int nt = 0; nt < 2; ++nt) {
      int n0 = nh * 32 + nt * 16;
      const ushort* bp = wint + (size_t)(n0 + col) * 128 + quad * 8;
      f4 acc = {0.f, 0.f, 0.f, 0.f};
      #pragma unroll
      for (int kf = 0; kf < 4; ++kf)
        acc = MFMA(a[kf], *(const bf8v*)(bp + kf * 32), acc);
      int c = n0 + col;
      float biv = b_in[c];
      #pragma unroll
      for (int r = 0; r < 4; ++r) {
        int tl = m0 + quad * 4 + r;
        hh[(size_t)(t0 + tl) * DMM + c] = acc[r] + biv;
      }
    }
  }
}

// ---------------------------------------------------------------------------
// x = LN1(mask*hh); pq=phi(x@wq+bq), pk=phi(x@wk+bk)*mask, vv=x@wv+bv  (bf16)
// ---------------------------------------------------------------------------
__global__ __launch_bounds__(512) void k_pre(
    const float* __restrict__ hh, const float* __restrict__ mask,
    const float* __restrict__ g1, const float* __restrict__ b1,
    const ushort* __restrict__ wqt, const float* __restrict__ bq,
    const ushort* __restrict__ wkt, const float* __restrict__ bk,
    const ushort* __restrict__ wvt, const float* __restrict__ bv,
    ushort* __restrict__ pq, ushort* __restrict__ pk, ushort* __restrict__ vv)
{
  __shared__ ushort xbf[64][72];
  __shared__ float mk[64];
  const int tid = threadIdx.x, lane = tid & 63, w = tid >> 6;
  const int t0 = blockIdx.x * 64;

  #pragma unroll
  for (int m = 0; m < 8; ++m) {
    int t = w * 8 + m;
    float mv = mask[t0 + t];
    float v = hh[(size_t)(t0 + t) * DMM + lane] * mv;
    float mean, var; wave_stats(v, mean, var);
    xbf[t][lane] = f2bf((v - mean) * rsqrtf(var + 1e-5f) * g1[lane] + b1[lane]);
    if (lane == 0) mk[t] = mv;
  }
  __syncthreads();

  const int col = lane & 15, quad = lane >> 4;
  const int m0 = (w >> 1) * 16, nh = w & 1;

  bf8v a0 = *(const bf8v*)&xbf[m0 + col][quad * 8];
  bf8v a1 = *(const bf8v*)&xbf[m0 + col][32 + quad * 8];

  f4 accq[2], acck[2], accv[2];
  #pragma unroll
  for (int nt = 0; nt < 2; ++nt) {
    int nr = nh * 32 + nt * 16 + col;
    const ushort* bpq = wqt + (size_t)nr * 64 + quad * 8;
    const ushort* bpk = wkt + (size_t)nr * 64 + quad * 8;
    const ushort* bpv = wvt + (size_t)nr * 64 + quad * 8;
    f4 z = {0.f, 0.f, 0.f, 0.f};
    accq[nt] = MFMA(a1, *(const bf8v*)(bpq + 32), MFMA(a0, *(const bf8v*)bpq, z));
    acck[nt] = MFMA(a1, *(const bf8v*)(bpk + 32), MFMA(a0, *(const bf8v*)bpk, z));
    accv[nt] = MFMA(a1, *(const bf8v*)(bpv + 32), MFMA(a0, *(const bf8v*)bpv, z));
  }
  #pragma unroll
  for (int nt = 0; nt < 2; ++nt) {
    int c = nh * 32 + nt * 16 + col;
    float bqv = bq[c], bkv = bk[c], bvv = bv[c];
    #pragma unroll
    for (int r = 0; r < 4; ++r) {
      int tl = m0 + quad * 4 + r;
      size_t o = (size_t)(t0 + tl) * DMM + c;
      pq[o] = f2bf(phi_elu(accq[nt][r] + bqv));
      pk[o] = f2bf(phi_elu(acck[nt][r] + bkv) * mk[tl]);
      vv[o] = f2bf(accv[nt][r] + bvv);
    }
  }
}

// ---------------------------------------------------------------------------
// kv/ksum partials per (b,h,split)
// ---------------------------------------------------------------------------
__global__ __launch_bounds__(256) void k_kv(
    const ushort* __restrict__ pk, const ushort* __restrict__ vv,
    float* __restrict__ part)
{
  const int bh = blockIdx.x / NSPLIT, sp = blockIdx.x % NSPLIT;
  const int b = bh >> 3, h = bh & 7;
  const int tid = threadIdx.x, lane = tid & 63, w = tid >> 6;

  float kv[8][8], ks[8];
  #pragma unroll
  for (int d = 0; d < 8; ++d) {
    ks[d] = 0.f;
    #pragma unroll
    for (int e = 0; e < 8; ++e) kv[d][e] = 0.f;
  }

  const int sbase = sp * (SS / NSPLIT) + w * (SS / NSPLIT / 4);
  for (int it = 0; it < SS / NSPLIT / 4 / 64; ++it) {
    int s = sbase + it * 64 + lane;
    size_t o = ((size_t)b * SS + s) * DMM + h * 8;
    bf8v pv = *(const bf8v*)(pk + o);
    bf8v uv = *(const bf8v*)(vv + o);
    float p[8], u[8];
    #pragma unroll
    for (int i = 0; i < 8; ++i) { p[i] = bf2f((ushort)pv[i]); u[i] = bf2f((ushort)uv[i]); }
    #pragma unroll
    for (int d = 0; d < 8; ++d) {
      ks[d] += p[d];
      #pragma unroll
      for (int e = 0; e < 8; ++e) kv[d][e] += p[d] * u[e];
    }
  }

  #pragma unroll
  for (int mk = 32; mk; mk >>= 1) {
    #pragma unroll
    for (int d = 0; d < 8; ++d) {
      ks[d] += __shfl_xor(ks[d], mk, 64);
      #pragma unroll
      for (int e = 0; e < 8; ++e) kv[d][e] += __shfl_xor(kv[d][e], mk, 64);
    }
  }

  __shared__ float red[4][72];
  if (lane == 0) {
    #pragma unroll
    for (int d = 0; d < 8; ++d) {
      red[w][64 + d] = ks[d];
      #pragma unroll
      for (int e = 0; e < 8; ++e) red[w][d * 8 + e] = kv[d][e];
    }
  }
  __syncthreads();
  if (tid < 72) {
    float s = red[0][tid] + red[1][tid] + red[2][tid] + red[3][tid];
    part[(size_t)blockIdx.x * 72 + tid] = s;
  }
}

// ---------------------------------------------------------------------------
// att = (pq@kv)/(pq.ksum+eps); hh = mask*hh + att@wo + bo;
// y = LN2(hh); hh += gelu(y@w1+b1)@w2 + b2     (64 tokens / block)
// ---------------------------------------------------------------------------
__global__ __launch_bounds__(512) void k_post(
    float* __restrict__ hh, const float* __restrict__ mask,
    const float* __restrict__ part, const ushort* __restrict__ pq,
    const ushort* __restrict__ wot, const float* __restrict__ bo,
    const float* __restrict__ g2, const float* __restrict__ b2ln,
    const ushort* __restrict__ w1t, const float* __restrict__ b1f,
    const ushort* __restrict__ w2t, const float* __restrict__ b2f)
{
  __shared__ union UU {
    struct { float pqL[64][64]; ushort attbf[64][72]; } a;
    ushort tfL[64][264];
  } U;
  __shared__ float hhL[64][64];
  __shared__ ushort ybf[64][72];
  __shared__ float kvL[8][72];

  const int tid = threadIdx.x, lane = tid & 63, w = tid >> 6;
  const int t0 = blockIdx.x * 64;
  const int b = t0 >> 12;

  for (int r = tid; r < 576; r += 512) {
    int h = r / 72, rr = r - h * 72;
    const float* pp = part + (size_t)(b * HH_ + h) * (NSPLIT * 72) + rr;
    kvL[h][rr] = pp[0] + pp[72] + pp[144] + pp[216];
  }
  #pragma unroll
  for (int i = 0; i < 8; ++i) {
    int idx = tid + 512 * i;
    int t = idx >> 6, k = idx & 63;
    U.a.pqL[t][k] = bf2f(pq[(size_t)(t0 + t) * DMM + k]);
    hhL[t][k] = hh[(size_t)(t0 + t) * DMM + k] * mask[t0 + t];
  }
  __syncthreads();

  {
    const int j = lane, h = j >> 3, e = j & 7;
    #pragma unroll
    for (int m = 0; m < 8; ++m) {
      int t = w * 8 + m;
      float num = 0.f, den = 1e-6f;
      #pragma unroll
      for (int d = 0; d < 8; ++d) {
        float p = U.a.pqL[t][h * 8 + d];
        num += p * kvL[h][d * 8 + e];
        den += p * kvL[h][64 + d];
      }
      U.a.attbf[t][j] = f2bf(num / den);
    }
  }
  __syncthreads();

  const int col = lane & 15, quad = lane >> 4;
  const int m0 = (w >> 1) * 16, nh = w & 1;

  // att @ wo + residual -> hhL
  {
    bf8v a0 = *(const bf8v*)&U.a.attbf[m0 + col][quad * 8];
    bf8v a1 = *(const bf8v*)&U.a.attbf[m0 + col][32 + quad * 8];
    #pragma unroll
    for (int nt = 0; nt < 2; ++nt) {
      int c = nh * 32 + nt * 16 + col;
      const ushort* bp = wot + (size_t)c * 64 + quad * 8;
      f4 z = {0.f, 0.f, 0.f, 0.f};
      f4 acc = MFMA(a1, *(const bf8v*)(bp + 32), MFMA(a0, *(const bf8v*)bp, z));
      float bov = bo[c];
      #pragma unroll
      for (int r = 0; r < 4; ++r) {
        int tl = m0 + quad * 4 + r;
        hhL[tl][c] += acc[r] + bov;
      }
    }
  }
  __syncthreads();

  // LN2
  #pragma unroll
  for (int m = 0; m < 8; ++m) {
    int t = w * 8 + m;
    float v = hhL[t][lane];
    float mean, var; wave_stats(v, mean, var);
    ybf[t][lane] = f2bf((v - mean) * rsqrtf(var + 1e-5f) * g2[lane] + b2ln[lane]);
  }
  __syncthreads();

  // FFN1 + gelu -> tfL (clobbers pqL/attbf: safe, last read before prev sync)
  {
    bf8v a0 = *(const bf8v*)&ybf[m0 + col][quad * 8];
    bf8v a1 = *(const bf8v*)&ybf[m0 + col][32 + quad * 8];
    #pragma unroll
    for (int nt = 0; nt < 8; ++nt) {
      int c = nh * 128 + nt * 16 + col;
      const ushort* bp = w1t + (size_t)c * 64 + quad * 8;
      f4 z = {0.f, 0.f, 0.f, 0.f};
      f4 acc = MFMA(a1, *(const bf8v*)(bp + 32), MFMA(a0, *(const bf8v*)bp, z));
      float b1v = b1f[c];
      #pragma unroll
      for (int r = 0; r < 4; ++r)
        U.tfL[m0 + quad * 4 + r][c] = f2bf(gelu_tanh(acc[r] + b1v));
    }
  }
  __syncthreads();

  // FFN2 + residual -> hh
  {
    bf8v af[8];
    #pragma unroll
    for (int kf = 0; kf < 8; ++kf)
      af[kf] = *(const bf8v*)&U.tfL[m0 + col][kf * 32 + quad * 8];
    #pragma unroll
    for (int nt = 0; nt < 2; ++nt) {
      int c = nh * 32 + nt * 16 + col;
      const ushort* bp = w2t + (size_t)c * 256 + quad * 8;
      f4 acc = {0.f, 0.f, 0.f, 0.f};
      #pragma unroll
      for (int kf = 0; kf < 8; ++kf)
        acc = MFMA(af[kf], *(const bf8v*)(bp + kf * 32), acc);
      float b2v = b2f[c];
      #pragma unroll
      for (int r = 0; r < 4; ++r) {
        int tl = m0 + quad * 4 + r;
        hh[(size_t)(t0 + tl) * DMM + c] = hhL[tl][c] + acc[r] + b2v;
      }
    }
  }
}

// ---------------------------------------------------------------------------
// out = (LNf(hh)*mask) @ wout + bout   (64 tokens / block, tile-major waves)
// ---------------------------------------------------------------------------
__global__ __launch_bounds__(512) void k_final(
    const float* __restrict__ hh, const float* __restrict__ mask,
    const float* __restrict__ gf, const float* __restrict__ bfn,
    const ushort* __restrict__ woutt, const float* __restrict__ bout,
    float* __restrict__ out)
{
  __shared__ ushort xbf[64][72];
  const int tid = threadIdx.x, lane = tid & 63, w = tid >> 6;
  const int t0 = blockIdx.x * 64;

  #pragma unroll
  for (int m = 0; m < 8; ++m) {
    int t = w * 8 + m;
    float v = hh[(size_t)(t0 + t) * DMM + lane];
    float mean, var; wave_stats(v, mean, var);
    xbf[t][lane] = f2bf(((v - mean) * rsqrtf(var + 1e-5f) * gf[lane] + bfn[lane]) * mask[t0 + t]);
  }
  __syncthreads();

  const int col = lane & 15, quad = lane >> 4;
  bf8v a0[4], a1[4];
  #pragma unroll
  for (int mt = 0; mt < 4; ++mt) {
    a0[mt] = *(const bf8v*)&xbf[mt * 16 + col][quad * 8];
    a1[mt] = *(const bf8v*)&xbf[mt * 16 + col][32 + quad * 8];
  }

  const int ts = w * 13, te = (ts + 13 < 102) ? ts + 13 : 102;
  for (int i = ts; i < te; ++i) {
    int c = i * 16 + col;
    int cr = c < CC ? c : CC - 1;
    const ushort* bp = woutt + (size_t)cr * 64 + quad * 8;
    bf8v b0 = *(const bf8v*)bp;
    bf8v b1 = *(const bf8v*)(bp + 32);
    float bov = bout[cr];
    #pragma unroll
    for (int mt = 0; mt < 4; ++mt) {
      f4 z = {0.f, 0.f, 0.f, 0.f};
      f4 acc = MFMA(a1[mt], b1, MFMA(a0[mt], b0, z));
      if (c < CC) {
        #pragma unroll
        for (int r = 0; r < 4; ++r) {
          int t = t0 + mt * 16 + quad * 4 + r;
          out[(size_t)t * CC + c] = acc[r] + bov;
        }
      }
    }
  }
}

// ---------------------------------------------------------------------------

extern "C" void kernel_launch(void* const* d_in, const int* in_sizes, int n_in,
                              void* d_out, int out_size, void* d_ws, size_t ws_size,
                              hipStream_t stream) {
  (void)in_sizes; (void)n_in; (void)out_size; (void)ws_size;
  const float* ex    = (const float*)d_in[0];
  const int*   labels= (const int*)  d_in[1];
  const float* mask  = (const float*)d_in[2];
  const float* we    = (const float*)d_in[3];
  const float* be    = (const float*)d_in[4];
  const float* lemb  = (const float*)d_in[5];
  const float* w_in  = (const float*)d_in[6];
  const float* b_in  = (const float*)d_in[7];
  const float* ln1s  = (const float*)d_in[8];
  const float* ln1b  = (const float*)d_in[9];
  const float* wq    = (const float*)d_in[10];
  const float* bq    = (const float*)d_in[11];
  const float* wk    = (const float*)d_in[12];
  const float* bk    = (const float*)d_in[13];
  const float* wv    = (const float*)d_in[14];
  const float* bv    = (const float*)d_in[15];
  const float* wo    = (const float*)d_in[16];
  const float* bo    = (const float*)d_in[17];
  const float* ln2s  = (const float*)d_in[18];
  const float* ln2b  = (const float*)d_in[19];
  const float* w1    = (const float*)d_in[20];
  const float* b1    = (const float*)d_in[21];
  const float* w2    = (const float*)d_in[22];
  const float* b2    = (const float*)d_in[23];
  const float* lnfs  = (const float*)d_in[24];
  const float* lnfb  = (const float*)d_in[25];
  const float* wout  = (const float*)d_in[26];
  const float* bout  = (const float*)d_in[27];

  char* p = (char*)d_ws;
  float*  hh   = (float*)p;  p += (size_t)NTOK * DMM * 4;
  ushort* pqb  = (ushort*)p; p += (size_t)NTOK * DMM * 2;
  ushort* pkb  = (ushort*)p; p += (size_t)NTOK * DMM * 2;
  ushort* vvb  = (ushort*)p; p += (size_t)NTOK * DMM * 2;
  float*  part = (float*)p;  p += (size_t)BB * HH_ * NSPLIT * 72 * 4;
  ushort* wet  = (ushort*)p; p += 128 * 128 * 2;
  ushort* wint = (ushort*)p; p += 64 * 128 * 2;
  ushort* wqt  = (ushort*)p; p += (size_t)LLAY * 64 * 64 * 2;
  ushort* wkt  = (ushort*)p; p += (size_t)LLAY * 64 * 64 * 2;
  ushort* wvt  = (ushort*)p; p += (size_t)LLAY * 64 * 64 * 2;
  ushort* wot  = (ushort*)p; p += (size_t)LLAY * 64 * 64 * 2;
  ushort* w1t  = (ushort*)p; p += (size_t)LLAY * 64 * 256 * 2;
  ushort* w2t  = (ushort*)p; p += (size_t)LLAY * 256 * 64 * 2;
  ushort* woutt= (ushort*)p; p += (size_t)64 * CC * 2;

  // weight conversions (bf16, transposed [n][k])
  k_convT<<<dim3(64, 1),  256, 0, stream>>>(we,   wet,  128, 128);
  k_convT<<<dim3(32, 1),  256, 0, stream>>>(w_in, wint, 128, 64);
  k_convT<<<dim3(16, LLAY), 256, 0, stream>>>(wq, wqt, 64, 64);
  k_convT<<<dim3(16, LLAY), 256, 0, stream>>>(wk, wkt, 64, 64);
  k_convT<<<dim3(16, LLAY), 256, 0, stream>>>(wv, wvt, 64, 64);
  k_convT<<<dim3(16, LLAY), 256, 0, stream>>>(wo, wot, 64, 64);
  k_convT<<<dim3(64, LLAY), 256, 0, stream>>>(w1, w1t, 64, 256);
  k_convT<<<dim3(64, LLAY), 256, 0, stream>>>(w2, w2t, 256, 64);
  k_convT<<<dim3((64 * CC + 255) / 256, 1), 256, 0, stream>>>(wout, woutt, 64, CC);

  k_embed<<<NTOK / 64, 512, 0, stream>>>(ex, labels, wet, be, lemb, wint, b_in, hh);

  for (int i = 0; i < LLAY; ++i) {
    k_pre<<<NTOK / 64, 512, 0, stream>>>(
        hh, mask, ln1s + i * DMM, ln1b + i * DMM,
        wqt + (size_t)i * DMM * DMM, bq + i * DMM,
        wkt + (size_t)i * DMM * DMM, bk + i * DMM,
        wvt + (size_t)i * DMM * DMM, bv + i * DMM,
        pqb, pkb, vvb);
    k_kv<<<BB * HH_ * NSPLIT, 256, 0, stream>>>(pkb, vvb, part);
    k_post<<<NTOK / 64, 512, 0, stream>>>(
        hh, mask, part, pqb,
        wot + (size_t)i * DMM * DMM, bo + i * DMM,
        ln2s + i * DMM, ln2b + i * DMM,
        w1t + (size_t)i * DMM * FFF, b1 + i * FFF,
        w2t + (size_t)i * FFF * DMM, b2 + i * DMM);
  }

  k_final<<<NTOK / 64, 512, 0, stream>>>(
      hh, mask, lnfs, lnfb, woutt, bout, (float*)d_out);
}